// Round 10
// baseline (367.365 us; speedup 1.0000x reference)
//
#include <hip/hip_runtime.h>

// Problem constants
#define N_NODES 4096
#define C_IN    256
#define HID     256
#define BATCH   8
#define R_TOT   32768   // BATCH * N_NODES

typedef unsigned short u16;
typedef short s8v  __attribute__((ext_vector_type(8)));   // 8 bf16 (bit pattern in shorts)
typedef float f4v  __attribute__((ext_vector_type(4)));
typedef u16   u16x4 __attribute__((ext_vector_type(4)));

#define MFMA(a,b,c) __builtin_amdgcn_mfma_f32_16x16x32_bf16((a),(b),(c),0,0,0)

__device__ __forceinline__ u16 bf_rne(float x) {
    unsigned u = __float_as_uint(x);
    u += 0x7fffu + ((u >> 16) & 1u);
    return (u16)(u >> 16);
}
__device__ __forceinline__ float bf_f(u16 h) {
    return __uint_as_float(((unsigned)h) << 16);
}
// fp32 -> bf16 hi/lo split: x ~= hi + lo, |err| <= 2^-18 |x|
__device__ __forceinline__ void split2f(float x, u16& h, u16& l) {
    h = bf_rne(x);
    l = bf_rne(x - bf_f(h));
}

// async global->LDS, 16B per lane. lds ptr must be wave-uniform (dest = base + lane*16)
__device__ __forceinline__ void glds16(const void* g, void* l) {
    __builtin_amdgcn_global_load_lds(
        (const __attribute__((address_space(1))) void*)g,
        (__attribute__((address_space(3))) void*)l, 16, 0, 0);
}

// ---------------- split kernels ----------------

// fused: G (4096x4096) -> bf16 hi;  X (32768x256) -> bf16 hi. float4-vectorized.
__global__ void splitGX_k(const float* __restrict__ G, u16* __restrict__ Gh,
                          const float* __restrict__ X, u16* __restrict__ Xh) {
    const int nG = 4194304;              // 16M floats / 4
    const int nTot = nG + 2097152;       // + 8M floats / 4
    int i = blockIdx.x * blockDim.x + threadIdx.x;
    const int stride = gridDim.x * blockDim.x;
    for (; i < nTot; i += stride) {
        const float4* src; u16x4* dst; int j;
        if (i < nG) { src = (const float4*)G; dst = (u16x4*)Gh; j = i; }
        else        { src = (const float4*)X; dst = (u16x4*)Xh; j = i - nG; }
        float4 x = src[j];
        u16x4 hh;
        hh[0] = bf_rne(x.x); hh[1] = bf_rne(x.y);
        hh[2] = bf_rne(x.z); hh[3] = bf_rne(x.w);
        dst[j] = hh;
    }
}

// transpose + split for both 256x256 weight matrices: out[h][c] = in[c][h]
__global__ void splitT2_k(const float* __restrict__ W1, u16* __restrict__ W1th,
                          u16* __restrict__ W1tl, const float* __restrict__ W2,
                          u16* __restrict__ W2th, u16* __restrict__ W2tl) {
    const float* in = blockIdx.y ? W2 : W1;
    u16* oh = blockIdx.y ? W2th : W1th;
    u16* ol = blockIdx.y ? W2tl : W1tl;
    const int c = blockIdx.x;      // row of in
    const int h = threadIdx.x;     // col of in
    float v = in[c * 256 + h];
    u16 hi, lo; split2f(v, hi, lo);
    oh[h * 256 + c] = hi;
    ol[h * 256 + c] = lo;
}

// ---------------- small GEMM: T[i=hid'][j=r] = sum_k Wt[i][k] * B[j][k] + bias[i] ----------------
// A (Wt) split hi/lo (x2 passes), B bf16-hi. All tiles staged via glds16 (pre-swizzled source).
// Output: bf16-hi, transposed layout [256][32768].
__global__ __launch_bounds__(256, 2) void gemm_small_k(
    const u16* __restrict__ Ah, const u16* __restrict__ Al,
    const u16* __restrict__ Bh,
    const float* __restrict__ bias, u16* __restrict__ Oh)
{
    __shared__ u16 sAh[4096], sAl[4096], sBh[4096];  // 128x32 each
    const int tid = threadIdx.x;
    const int w = tid >> 6, lane = tid & 63;
    const int i0 = blockIdx.x * 128;   // output row tile (hid')
    const int r0 = blockIdx.y * 128;   // output col tile (r)
    const int lr = lane & 15, lk = lane >> 4;
    const int wr = (w >> 1) * 64, wc = (w & 1) * 64;
    const int kslot = (lk ^ ((lr >> 1) & 3)) * 8;   // swizzled read slot (u16 units)
    const int cb = ((lane & 3) ^ ((lane >> 3) & 3)) * 8;  // pre-swizzled source slot

    const u16 *pAh[2], *pAl[2], *pBh[2];
#pragma unroll
    for (int j = 0; j < 2; ++j) {
        const int ra = i0 + (w * 2 + j) * 16 + (lane >> 2);
        pAh[j] = Ah + (size_t)ra * 256 + cb;
        pAl[j] = Al + (size_t)ra * 256 + cb;
        const int rb = r0 + (w * 2 + j) * 16 + (lane >> 2);
        pBh[j] = Bh + (size_t)rb * 256 + cb;
    }

    f4v acc[4][4] = {};

    for (int kt = 0; kt < 8; ++kt) {
#pragma unroll
        for (int j = 0; j < 2; ++j) {
            glds16(pAh[j] + kt * 32, sAh + (w * 2 + j) * 512);
            glds16(pAl[j] + kt * 32, sAl + (w * 2 + j) * 512);
            glds16(pBh[j] + kt * 32, sBh + (w * 2 + j) * 512);
        }
        __syncthreads();

        s8v fah[4], fal[4], fbh[4];
#pragma unroll
        for (int m = 0; m < 4; ++m) {
            fah[m] = *(const s8v*)(sAh + (wr + m * 16 + lr) * 32 + kslot);
            fal[m] = *(const s8v*)(sAl + (wr + m * 16 + lr) * 32 + kslot);
            fbh[m] = *(const s8v*)(sBh + (wc + m * 16 + lr) * 32 + kslot);
        }
#pragma unroll
        for (int m = 0; m < 4; ++m)
#pragma unroll
            for (int n = 0; n < 4; ++n)
                acc[m][n] = MFMA(fah[m], fbh[n], acc[m][n]);
#pragma unroll
        for (int m = 0; m < 4; ++m)
#pragma unroll
            for (int n = 0; n < 4; ++n)
                acc[m][n] = MFMA(fal[m], fbh[n], acc[m][n]);
        __syncthreads();
    }

    // epilogue: +bias, round to bf16-hi, store transposed output [hid'][32768]
#pragma unroll
    for (int m = 0; m < 4; ++m) {
#pragma unroll
        for (int q = 0; q < 4; ++q) {
            const int rowg = i0 + wr + m * 16 + lk * 4 + q;
            const float bv = bias[rowg];
#pragma unroll
            for (int n = 0; n < 4; ++n) {
                const int colg = r0 + wc + n * 16 + lr;
                float v = acc[m][n][q] + bv;
                Oh[(size_t)rowg * R_TOT + colg] = bf_rne(v);
            }
        }
    }
}

// ---------------- big GEMM: H[b][i=n][j=h] = relu( sum_m Ghi[i][m] * Thi[j][b*4096+m] ) ----------------
// Pure bf16. BM=256 BN=128 BK=64, 8 waves (4Mx2N, wave 64x64). LDS stages A ONLY
// (3 x 32KB triple buffer); B fragments read DIRECTLY from global (L2-resident panel,
// 4-wave reuse -> L1 hits), double-buffered in registers one tile ahead.
// A swizzle unchanged: read slot s' = (ks*4+lk) ^ (row&7); source pre-swizzled (l&7)^(l>>3).
__global__ __launch_bounds__(512, 2) void gemm_big_k(
    const u16* __restrict__ Gh, const u16* __restrict__ Th,
    u16* __restrict__ Hh)
{
    extern __shared__ u16 lds[];   // 3 * 16384 u16 = 98304 B (A tiles only)
    const int tid = threadIdx.x;
    const int w = tid >> 6, l = tid & 63;
    const int n0 = blockIdx.x * 256;
    const int h0 = blockIdx.y * 128;
    const int b  = blockIdx.z;
    const int lr = l & 15, lk = l >> 4;
    const int wm = w >> 1, wn = w & 1;
    // A fragment read slots (u16 units): s' = (ks*4+lk) ^ (lr&7)
    const int sl0 = ((lk)     ^ (lr & 7)) * 8;
    const int sl1 = ((4 + lk) ^ (lr & 7)) * 8;

    // A staging: per-lane source swizzle (chunk = 8 rows x 64 u16)
    const int srow  = l >> 3;
    const int sslot = ((l & 7) ^ srow) * 8;

    const u16* pA0 = Gh + (size_t)(n0 + 8 * w + srow) * 4096 + sslot;
    const u16* pA1 = pA0 + (size_t)64  * 4096;
    const u16* pA2 = pA0 + (size_t)128 * 4096;
    const u16* pA3 = pA0 + (size_t)192 * 4096;
    const int dA0 = w * 512, dA1 = (w + 8) * 512, dA2 = (w + 16) * 512, dA3 = (w + 24) * 512;

    // B fragment bases (global), n = 0..3; k advances 64/tile, ks offset = +32
    const u16* pB[4];
#pragma unroll
    for (int n = 0; n < 4; ++n)
        pB[n] = Th + (size_t)(h0 + wn * 64 + n * 16 + lr) * R_TOT
                   + (size_t)b * 4096 + lk * 8;

    f4v acc[4][4] = {};
    s8v bbA[8], bbB[8];   // B frag double buffer: [0..3]=ks0, [4..7]=ks1

#define STAGEA(STG) do {                                                       \
    u16* Ls = lds + (STG) * 16384;                                             \
    glds16(pA0, Ls + dA0); glds16(pA1, Ls + dA1);                              \
    glds16(pA2, Ls + dA2); glds16(pA3, Ls + dA3);                              \
    pA0 += 64; pA1 += 64; pA2 += 64; pA3 += 64;                                \
} while (0)

// One K-tile, 2 phases. This tile's B frags are in BBC; prefetch next tile's into BBN.
// VMODE: 0 = vmcnt(16) steady, 1 = vmcnt(12) (t=62), 2 = skip (t=63).
#define KTILE(CUR, STG, BBC, BBN, DO_STAGE, DO_B, VMODE) do {                  \
    const u16* Lc = lds + (CUR) * 16384;                                       \
    /* P0: ds_read A ks0; issue next-tile B ks0 loads */                       \
    { s8v fa[4];                                                               \
      _Pragma("unroll") for (int m = 0; m < 4; ++m)                            \
          fa[m] = *(const s8v*)(Lc + (wm * 64 + m * 16 + lr) * 64 + sl0);      \
      if (DO_B) {                                                              \
          _Pragma("unroll") for (int n = 0; n < 4; ++n)                        \
              BBN[n] = *(const s8v*)(pB[n] + 64);                              \
      }                                                                        \
      __builtin_amdgcn_s_barrier();                                            \
      __builtin_amdgcn_s_setprio(1);                                           \
      _Pragma("unroll") for (int m = 0; m < 4; ++m)                            \
          _Pragma("unroll") for (int n = 0; n < 4; ++n)                        \
              acc[m][n] = MFMA(fa[m], BBC[n], acc[m][n]);                      \
      __builtin_amdgcn_s_setprio(0);                                           \
      __builtin_amdgcn_s_barrier(); }                                          \
    /* P1: ds_read A ks1; stage A(t+2); issue next-tile B ks1 loads */         \
    { s8v fa[4];                                                               \
      _Pragma("unroll") for (int m = 0; m < 4; ++m)                            \
          fa[m] = *(const s8v*)(Lc + (wm * 64 + m * 16 + lr) * 64 + sl1);      \
      if (DO_STAGE) STAGEA(STG);                                               \
      if (DO_B) {                                                              \
          _Pragma("unroll") for (int n = 0; n < 4; ++n)                        \
              BBN[4 + n] = *(const s8v*)(pB[n] + 96);                          \
      }                                                                        \
      __builtin_amdgcn_s_barrier();                                            \
      __builtin_amdgcn_s_setprio(1);                                           \
      _Pragma("unroll") for (int m = 0; m < 4; ++m)                            \
          _Pragma("unroll") for (int n = 0; n < 4; ++n)                        \
              acc[m][n] = MFMA(fa[m], BBC[4 + n], acc[m][n]);                  \
      __builtin_amdgcn_s_setprio(0); }                                         \
    if (DO_B) { _Pragma("unroll") for (int n = 0; n < 4; ++n) pB[n] += 64; }   \
    __builtin_amdgcn_sched_barrier(0);                                         \
    if (VMODE == 0)      asm volatile("s_waitcnt vmcnt(16)" ::: "memory");     \
    else if (VMODE == 1) asm volatile("s_waitcnt vmcnt(12)" ::: "memory");     \
    if (VMODE != 2) __builtin_amdgcn_s_barrier();                              \
    __builtin_amdgcn_sched_barrier(0);                                         \
} while (0)

    // prologue: stage A tiles 0,1; load B tile 0 into bbA
    STAGEA(0);
    STAGEA(1);
#pragma unroll
    for (int n = 0; n < 4; ++n) bbA[n]     = *(const s8v*)(pB[n]);
#pragma unroll
    for (int n = 0; n < 4; ++n) bbA[4 + n] = *(const s8v*)(pB[n] + 32);
    asm volatile("s_waitcnt vmcnt(12)" ::: "memory");   // A(0) landed
    __builtin_amdgcn_s_barrier();
    __builtin_amdgcn_sched_barrier(0);

    // 64 K-tiles; LDS buf period 3, B reg buf period 2 -> 6-tile pattern
    for (int it = 0; it < 10; ++it) {
        KTILE(0, 2, bbA, bbB, 1, 1, 0);
        KTILE(1, 0, bbB, bbA, 1, 1, 0);
        KTILE(2, 1, bbA, bbB, 1, 1, 0);
        KTILE(0, 2, bbB, bbA, 1, 1, 0);
        KTILE(1, 0, bbA, bbB, 1, 1, 0);
        KTILE(2, 1, bbB, bbA, 1, 1, 0);
    }
    KTILE(0, 2, bbA, bbB, 1, 1, 0);   // t=60 (stages A62, loads B61)
    KTILE(1, 0, bbB, bbA, 1, 1, 0);   // t=61 (stages A63, loads B62)
    KTILE(2, 1, bbA, bbB, 0, 1, 1);   // t=62 (loads B63)
    KTILE(0, 2, bbB, bbA, 0, 0, 2);   // t=63

#undef STAGEA
#undef KTILE

    // epilogue: relu, round, store H as bf16-hi [b*4096+row][col]
    const size_t obase = ((size_t)b * 4096 + n0 + wm * 64 + lk * 4) * 256
                       + h0 + wn * 64 + lr;
#pragma unroll
    for (int m = 0; m < 4; ++m)
#pragma unroll
        for (int n = 0; n < 4; ++n)
#pragma unroll
            for (int q = 0; q < 4; ++q) {
                float v = acc[m][n][q];
                v = v > 0.f ? v : 0.f;
                Hh[obase + (size_t)(m * 16 + q) * 256 + n * 16] = bf_rne(v);
            }
}

// ---------------- final MLP (MFMA): out[r] = relu(H[r,:] @ Wm1 + bm1) @ Wm2 + bm2 ----------------
__global__ __launch_bounds__(256) void mlp_k(
    const u16* __restrict__ Hh, const float* __restrict__ Wm1,
    const float* __restrict__ bm1, const float* __restrict__ Wm2,
    const float* __restrict__ bm2, float* __restrict__ out)
{
    __shared__ u16 sB[16384];   // Wm1t bf16, swizzled: [col 64][k 256]
    const int tid = threadIdx.x;
    const int w = tid >> 6, l = tid & 63;
    const int lr = l & 15, lk = l >> 4;

    // stage Wm1^T: coalesced read Wm1[k][col], bf16 round, XOR-swizzled ds_write
    for (int idx = tid; idx < 16384; idx += 256) {
        const int col = idx & 63, k = idx >> 6;
        const int slot = (k >> 3) ^ (col & 7);
        sB[col * 256 + slot * 8 + (k & 7)] = bf_rne(Wm1[k * 64 + col]);
    }
    __syncthreads();

    // per-lane epilogue constants
    float bm1v[4], w2v[4];
#pragma unroll
    for (int n = 0; n < 4; ++n) {
        bm1v[n] = bm1[n * 16 + lr];
        w2v[n]  = Wm2[n * 16 + lr];
    }
    const float b2v = bm2[0];

    const int rowbase = blockIdx.x * 128 + w * 32;
    f4v acc[2][4] = {};
#pragma unroll
    for (int ks = 0; ks < 8; ++ks) {
        s8v fa[2], fb[4];
#pragma unroll
        for (int m = 0; m < 2; ++m)
            fa[m] = *(const s8v*)(Hh + (size_t)(rowbase + m * 16 + lr) * 256 + ks * 32 + lk * 8);
        const int slot = ((ks * 4 + lk) ^ (lr & 7)) * 8;
#pragma unroll
        for (int n = 0; n < 4; ++n)
            fb[n] = *(const s8v*)(sB + (n * 16 + lr) * 256 + slot);
#pragma unroll
        for (int m = 0; m < 2; ++m)
#pragma unroll
            for (int n = 0; n < 4; ++n)
                acc[m][n] = MFMA(fa[m], fb[n], acc[m][n]);
    }

    // epilogue: +bm1, relu, xWm2, reduce over 64 cols (16-lane butterfly), +bm2
#pragma unroll
    for (int m = 0; m < 2; ++m)
#pragma unroll
        for (int q = 0; q < 4; ++q) {
            float p = 0.f;
#pragma unroll
            for (int n = 0; n < 4; ++n) {
                float v = acc[m][n][q] + bm1v[n];
                v = v > 0.f ? v : 0.f;
                p += v * w2v[n];
            }
#pragma unroll
            for (int mask = 1; mask < 16; mask <<= 1)
                p += __shfl_xor(p, mask);
            if (lr == 0)
                out[rowbase + m * 16 + lk * 4 + q] = p + b2v;
        }
}

// ---------------- launch ----------------
extern "C" void kernel_launch(void* const* d_in, const int* in_sizes, int n_in,
                              void* d_out, int out_size, void* d_ws, size_t ws_size,
                              hipStream_t stream) {
    (void)in_sizes; (void)n_in; (void)out_size; (void)ws_size;
    const float* X   = (const float*)d_in[0];
    const float* G   = (const float*)d_in[1];
    const float* W1  = (const float*)d_in[2];
    const float* b1  = (const float*)d_in[3];
    const float* W2  = (const float*)d_in[4];
    const float* b2  = (const float*)d_in[5];
    const float* Wm1 = (const float*)d_in[6];
    const float* bm1 = (const float*)d_in[7];
    const float* Wm2 = (const float*)d_in[8];
    const float* bm2 = (const float*)d_in[9];
    float* out = (float*)d_out;

    char* ws = (char*)d_ws;
    u16* Gh   = (u16*)(ws);                     // 33554432 B (bf16 hi)
    u16* W1th = (u16*)(ws + 67108864u);         // 131072 B
    u16* W1tl = (u16*)(ws + 67239936u);
    u16* W2th = (u16*)(ws + 67371008u);
    u16* W2tl = (u16*)(ws + 67502080u);
    u16* Tth  = (u16*)(ws + 67633152u);         // 16777216 B (bf16 hi)
    u16* XHh  = (u16*)(ws + 101187584u);        // 16777216 B (X-hi, then H1-hi, then H2-hi)

    // split G and X to bf16-hi (fused); split+transpose W1/W2 (fused)
    splitGX_k<<<3072, 256, 0, stream>>>(G, Gh, X, XHh);
    splitT2_k<<<dim3(256, 2), 256, 0, stream>>>(W1, W1th, W1tl, W2, W2th, W2tl);

    // conv1 pre-prop: T1t = bf16((X @ W1 + b1)^T)
    gemm_small_k<<<dim3(2, 256), 256, 0, stream>>>(W1th, W1tl, XHh, b1, Tth);
    // conv1 prop: H1 = bf16(relu(G @ T1)) (overwrites X buffer)
    gemm_big_k<<<dim3(16, 2, 8), 512, 98304, stream>>>(Gh, Tth, XHh);
    // conv2 pre-prop: T2t = bf16((H1 @ W2 + b2)^T)
    gemm_small_k<<<dim3(2, 256), 256, 0, stream>>>(W2th, W2tl, XHh, b2, Tth);
    // conv2 prop: H2 = bf16(relu(G @ T2))
    gemm_big_k<<<dim3(16, 2, 8), 512, 98304, stream>>>(Gh, Tth, XHh);
    // final MLP (MFMA)
    mlp_k<<<256, 256, 0, stream>>>(XHh, Wm1, bm1, Wm2, bm2, out);
}

// Round 11
// 182.563 us; speedup vs baseline: 2.0123x; 2.0123x over previous
//
#include <hip/hip_runtime.h>

// Problem constants
#define N_NODES 4096
#define C_IN    256
#define HID     256
#define BATCH   8
#define R_TOT   32768   // BATCH * N_NODES

typedef unsigned short u16;
typedef short s8v  __attribute__((ext_vector_type(8)));   // 8 bf16 (bit pattern in shorts)
typedef float f4v  __attribute__((ext_vector_type(4)));
typedef u16   u16x4 __attribute__((ext_vector_type(4)));

#define MFMA(a,b,c) __builtin_amdgcn_mfma_f32_16x16x32_bf16((a),(b),(c),0,0,0)

__device__ __forceinline__ u16 bf_rne(float x) {
    unsigned u = __float_as_uint(x);
    u += 0x7fffu + ((u >> 16) & 1u);
    return (u16)(u >> 16);
}
__device__ __forceinline__ float bf_f(u16 h) {
    return __uint_as_float(((unsigned)h) << 16);
}

// async global->LDS, 16B per lane. lds ptr must be wave-uniform (dest = base + lane*16)
__device__ __forceinline__ void glds16(const void* g, void* l) {
    __builtin_amdgcn_global_load_lds(
        (const __attribute__((address_space(1))) void*)g,
        (__attribute__((address_space(3))) void*)l, 16, 0, 0);
}

// ---------------- split kernels ----------------

// fused: G (4096x4096) -> bf16 hi;  X (32768x256) -> bf16 hi. float4-vectorized.
__global__ void splitGX_k(const float* __restrict__ G, u16* __restrict__ Gh,
                          const float* __restrict__ X, u16* __restrict__ Xh) {
    const int nG = 4194304;              // 16M floats / 4
    const int nTot = nG + 2097152;       // + 8M floats / 4
    int i = blockIdx.x * blockDim.x + threadIdx.x;
    const int stride = gridDim.x * blockDim.x;
    for (; i < nTot; i += stride) {
        const float4* src; u16x4* dst; int j;
        if (i < nG) { src = (const float4*)G; dst = (u16x4*)Gh; j = i; }
        else        { src = (const float4*)X; dst = (u16x4*)Xh; j = i - nG; }
        float4 x = src[j];
        u16x4 hh;
        hh[0] = bf_rne(x.x); hh[1] = bf_rne(x.y);
        hh[2] = bf_rne(x.z); hh[3] = bf_rne(x.w);
        dst[j] = hh;
    }
}

// transpose + bf16-round both 256x256 weight matrices: out[h][c] = bf16(in[c][h])
__global__ void splitT2_k(const float* __restrict__ W1, u16* __restrict__ W1th,
                          const float* __restrict__ W2, u16* __restrict__ W2th) {
    const float* in = blockIdx.y ? W2 : W1;
    u16* oh = blockIdx.y ? W2th : W1th;
    const int c = blockIdx.x;      // row of in
    const int h = threadIdx.x;     // col of in
    oh[h * 256 + c] = bf_rne(in[c * 256 + h]);
}

// ---------------- small GEMM: T[i=hid'][j=r] = sum_k Wt[i][k] * B[j][k] + bias[i] ----------------
// Pure bf16 (x1). A (Wt) and B bf16-hi, staged via glds16 (pre-swizzled source).
// Output: bf16-hi, transposed layout [256][32768].
__global__ __launch_bounds__(256, 2) void gemm_small_k(
    const u16* __restrict__ Ah, const u16* __restrict__ Bh,
    const float* __restrict__ bias, u16* __restrict__ Oh)
{
    __shared__ u16 sAh[4096], sBh[4096];  // 128x32 each
    const int tid = threadIdx.x;
    const int w = tid >> 6, lane = tid & 63;
    const int i0 = blockIdx.x * 128;   // output row tile (hid')
    const int r0 = blockIdx.y * 128;   // output col tile (r)
    const int lr = lane & 15, lk = lane >> 4;
    const int wr = (w >> 1) * 64, wc = (w & 1) * 64;
    const int kslot = (lk ^ ((lr >> 1) & 3)) * 8;   // swizzled read slot (u16 units)
    const int cb = ((lane & 3) ^ ((lane >> 3) & 3)) * 8;  // pre-swizzled source slot

    const u16 *pAh[2], *pBh[2];
#pragma unroll
    for (int j = 0; j < 2; ++j) {
        const int ra = i0 + (w * 2 + j) * 16 + (lane >> 2);
        pAh[j] = Ah + (size_t)ra * 256 + cb;
        const int rb = r0 + (w * 2 + j) * 16 + (lane >> 2);
        pBh[j] = Bh + (size_t)rb * 256 + cb;
    }

    f4v acc[4][4] = {};

    for (int kt = 0; kt < 8; ++kt) {
#pragma unroll
        for (int j = 0; j < 2; ++j) {
            glds16(pAh[j] + kt * 32, sAh + (w * 2 + j) * 512);
            glds16(pBh[j] + kt * 32, sBh + (w * 2 + j) * 512);
        }
        __syncthreads();

        s8v fah[4], fbh[4];
#pragma unroll
        for (int m = 0; m < 4; ++m) {
            fah[m] = *(const s8v*)(sAh + (wr + m * 16 + lr) * 32 + kslot);
            fbh[m] = *(const s8v*)(sBh + (wc + m * 16 + lr) * 32 + kslot);
        }
#pragma unroll
        for (int m = 0; m < 4; ++m)
#pragma unroll
            for (int n = 0; n < 4; ++n)
                acc[m][n] = MFMA(fah[m], fbh[n], acc[m][n]);
        __syncthreads();
    }

    // epilogue: +bias, round to bf16-hi, store transposed output [hid'][32768]
#pragma unroll
    for (int m = 0; m < 4; ++m) {
#pragma unroll
        for (int q = 0; q < 4; ++q) {
            const int rowg = i0 + wr + m * 16 + lk * 4 + q;
            const float bv = bias[rowg];
#pragma unroll
            for (int n = 0; n < 4; ++n) {
                const int colg = r0 + wc + n * 16 + lr;
                float v = acc[m][n][q] + bv;
                Oh[(size_t)rowg * R_TOT + colg] = bf_rne(v);
            }
        }
    }
}

// ---------------- big GEMM: H[b][i=n][j=h] = relu( sum_m Ghi[i][m] * Thi[j][b*4096+m] ) ----------------
// Round-8 proven kernel. Pure bf16. BM=256 BN=128 BK=64, 8 waves (4Mx2N, per-wave 64x64),
// triple-buffered LDS (3 x 48KB), 2 phases/K-tile (ks0 | ks1), counted vmcnt(6),
// setprio around MFMA. Row = 64 u16 = 128B; swizzle: slot s' = (ks*4+lk) ^ (row&7).
// Staging: per-wave 1KB chunks (8 rows x 64 u16), source pre-swizzled by (l&7)^(l>>3).
// Buffer layout (u16): [A 256x64 | B 128x64] = 24576 u16 = 48KB. Output: bf16-hi only.
__global__ __launch_bounds__(512, 2) void gemm_big_k(
    const u16* __restrict__ Gh, const u16* __restrict__ Th,
    u16* __restrict__ Hh)
{
    extern __shared__ u16 lds[];   // 3 * 24576 u16 = 147456 B
    const int tid = threadIdx.x;
    const int w = tid >> 6, l = tid & 63;
    const int n0 = blockIdx.x * 256;
    const int h0 = blockIdx.y * 128;
    const int b  = blockIdx.z;
    const int lr = l & 15, lk = l >> 4;
    const int wm = w >> 1, wn = w & 1;
    // fragment read slots (u16 units): s' = (ks*4+lk) ^ (lr&7)
    const int sl0 = ((lk)     ^ (lr & 7)) * 8;
    const int sl1 = ((4 + lk) ^ (lr & 7)) * 8;

    // staging: per-lane source swizzle (chunk = 8 rows x 64 u16)
    const int srow  = l >> 3;                   // row within chunk
    const int sslot = ((l & 7) ^ srow) * 8;     // source col slot (u16)

    // A chunks c = w, w+8, w+16, w+24 (rows 8c..8c+7); B chunks c = w, w+8
    const u16* pA0 = Gh + (size_t)(n0 + 8 * w        + srow) * 4096 + sslot;
    const u16* pA1 = Gh + (size_t)(n0 + 8 * (w + 8)  + srow) * 4096 + sslot;
    const u16* pA2 = Gh + (size_t)(n0 + 8 * (w + 16) + srow) * 4096 + sslot;
    const u16* pA3 = Gh + (size_t)(n0 + 8 * (w + 24) + srow) * 4096 + sslot;
    const u16* pB0 = Th + (size_t)(h0 + 8 * w       + srow) * R_TOT + (size_t)b * 4096 + sslot;
    const u16* pB1 = Th + (size_t)(h0 + 8 * (w + 8) + srow) * R_TOT + (size_t)b * 4096 + sslot;

    // wave-uniform LDS chunk bases (u16)
    const int dA0 = w * 512, dA1 = (w + 8) * 512, dA2 = (w + 16) * 512, dA3 = (w + 24) * 512;
    const int dB0 = 16384 + w * 512, dB1 = 16384 + (w + 8) * 512;

    f4v acc[4][4] = {};

#define STAGE6(STG) do {                                                       \
    u16* Ls = lds + (STG) * 24576;                                             \
    glds16(pA0, Ls + dA0); glds16(pA1, Ls + dA1);                              \
    glds16(pA2, Ls + dA2); glds16(pA3, Ls + dA3);                              \
    glds16(pB0, Ls + dB0); glds16(pB1, Ls + dB1);                              \
    pA0 += 64; pA1 += 64; pA2 += 64; pA3 += 64; pB0 += 64; pB1 += 64;          \
} while (0)

// One K-tile: 2 phases. VMODE: 0 = vmcnt(6) (steady), 1 = vmcnt(0) (drain), 2 = skip.
#define KTILE(CUR, STG, DO_STAGE, VMODE) do {                                  \
    const u16* Lc = lds + (CUR) * 24576;                                       \
    u16* Ls = lds + (STG) * 24576;                                             \
    /* P0: ks0 fragments; stage first 3 chunks */                              \
    { s8v fa[4], fb[4];                                                        \
      _Pragma("unroll") for (int m = 0; m < 4; ++m)                            \
          fa[m] = *(const s8v*)(Lc + (wm * 64 + m * 16 + lr) * 64 + sl0);      \
      _Pragma("unroll") for (int n = 0; n < 4; ++n)                            \
          fb[n] = *(const s8v*)(Lc + 16384 + (wn * 64 + n * 16 + lr) * 64 + sl0); \
      if (DO_STAGE) { glds16(pA0, Ls + dA0); glds16(pA1, Ls + dA1);            \
                      glds16(pB0, Ls + dB0); }                                 \
      __builtin_amdgcn_s_barrier();                                            \
      __builtin_amdgcn_s_setprio(1);                                           \
      _Pragma("unroll") for (int m = 0; m < 4; ++m)                            \
          _Pragma("unroll") for (int n = 0; n < 4; ++n)                        \
              acc[m][n] = MFMA(fa[m], fb[n], acc[m][n]);                       \
      __builtin_amdgcn_s_setprio(0);                                           \
      __builtin_amdgcn_s_barrier(); }                                          \
    /* P1: ks1 fragments; stage last 3 chunks, advance ptrs */                 \
    { s8v fa[4], fb[4];                                                        \
      _Pragma("unroll") for (int m = 0; m < 4; ++m)                            \
          fa[m] = *(const s8v*)(Lc + (wm * 64 + m * 16 + lr) * 64 + sl1);      \
      _Pragma("unroll") for (int n = 0; n < 4; ++n)                            \
          fb[n] = *(const s8v*)(Lc + 16384 + (wn * 64 + n * 16 + lr) * 64 + sl1); \
      if (DO_STAGE) { glds16(pA2, Ls + dA2); glds16(pA3, Ls + dA3);            \
                      glds16(pB1, Ls + dB1);                                   \
                      pA0 += 64; pA1 += 64; pA2 += 64; pA3 += 64;              \
                      pB0 += 64; pB1 += 64; }                                  \
      __builtin_amdgcn_s_barrier();                                            \
      __builtin_amdgcn_s_setprio(1);                                           \
      _Pragma("unroll") for (int m = 0; m < 4; ++m)                            \
          _Pragma("unroll") for (int n = 0; n < 4; ++n)                        \
              acc[m][n] = MFMA(fa[m], fb[n], acc[m][n]);                       \
      __builtin_amdgcn_s_setprio(0); }                                         \
    if (VMODE == 0)      asm volatile("s_waitcnt vmcnt(6)" ::: "memory");      \
    else if (VMODE == 1) asm volatile("s_waitcnt vmcnt(0)" ::: "memory");      \
    if (VMODE != 2) __builtin_amdgcn_s_barrier();                              \
    __builtin_amdgcn_sched_barrier(0);                                         \
} while (0)

    // prologue: stage tiles 0 (buf0) and 1 (buf1); 12 loads in flight per wave
    STAGE6(0);
    STAGE6(1);
    asm volatile("s_waitcnt vmcnt(6)" ::: "memory");   // tile-0 loads landed
    __builtin_amdgcn_s_barrier();
    __builtin_amdgcn_sched_barrier(0);

    // 64 K-tiles: t in buf t%3, staging t+2 while computing t (t <= 61)
    for (int it = 0; it < 20; ++it) {
        KTILE(0, 2, 1, 0);
        KTILE(1, 0, 1, 0);
        KTILE(2, 1, 1, 0);
    }
    KTILE(0, 2, 1, 0);   // t=60, stages 62
    KTILE(1, 0, 1, 0);   // t=61, stages 63
    KTILE(2, 1, 0, 1);   // t=62, drain tile-63 loads
    KTILE(0, 2, 0, 2);   // t=63

#undef STAGE6
#undef KTILE

    // epilogue: relu, round, store H as bf16-hi [b*4096+row][col]
    const size_t obase = ((size_t)b * 4096 + n0 + wm * 64 + lk * 4) * 256
                       + h0 + wn * 64 + lr;
#pragma unroll
    for (int m = 0; m < 4; ++m)
#pragma unroll
        for (int n = 0; n < 4; ++n)
#pragma unroll
            for (int q = 0; q < 4; ++q) {
                float v = acc[m][n][q];
                v = v > 0.f ? v : 0.f;
                Hh[obase + (size_t)(m * 16 + q) * 256 + n * 16] = bf_rne(v);
            }
}

// ---------------- final MLP (MFMA): out[r] = relu(H[r,:] @ Wm1 + bm1) @ Wm2 + bm2 ----------------
__global__ __launch_bounds__(256) void mlp_k(
    const u16* __restrict__ Hh, const float* __restrict__ Wm1,
    const float* __restrict__ bm1, const float* __restrict__ Wm2,
    const float* __restrict__ bm2, float* __restrict__ out)
{
    __shared__ u16 sB[16384];   // Wm1t bf16, swizzled: [col 64][k 256]
    const int tid = threadIdx.x;
    const int w = tid >> 6, l = tid & 63;
    const int lr = l & 15, lk = l >> 4;

    // stage Wm1^T: coalesced read Wm1[k][col], bf16 round, XOR-swizzled ds_write
    for (int idx = tid; idx < 16384; idx += 256) {
        const int col = idx & 63, k = idx >> 6;
        const int slot = (k >> 3) ^ (col & 7);
        sB[col * 256 + slot * 8 + (k & 7)] = bf_rne(Wm1[k * 64 + col]);
    }
    __syncthreads();

    // per-lane epilogue constants
    float bm1v[4], w2v[4];
#pragma unroll
    for (int n = 0; n < 4; ++n) {
        bm1v[n] = bm1[n * 16 + lr];
        w2v[n]  = Wm2[n * 16 + lr];
    }
    const float b2v = bm2[0];

    const int rowbase = blockIdx.x * 128 + w * 32;
    f4v acc[2][4] = {};
#pragma unroll
    for (int ks = 0; ks < 8; ++ks) {
        s8v fa[2], fb[4];
#pragma unroll
        for (int m = 0; m < 2; ++m)
            fa[m] = *(const s8v*)(Hh + (size_t)(rowbase + m * 16 + lr) * 256 + ks * 32 + lk * 8);
        const int slot = ((ks * 4 + lk) ^ (lr & 7)) * 8;
#pragma unroll
        for (int n = 0; n < 4; ++n)
            fb[n] = *(const s8v*)(sB + (n * 16 + lr) * 256 + slot);
#pragma unroll
        for (int m = 0; m < 2; ++m)
#pragma unroll
            for (int n = 0; n < 4; ++n)
                acc[m][n] = MFMA(fa[m], fb[n], acc[m][n]);
    }

    // epilogue: +bm1, relu, xWm2, reduce over 64 cols (16-lane butterfly), +bm2
#pragma unroll
    for (int m = 0; m < 2; ++m)
#pragma unroll
        for (int q = 0; q < 4; ++q) {
            float p = 0.f;
#pragma unroll
            for (int n = 0; n < 4; ++n) {
                float v = acc[m][n][q] + bm1v[n];
                v = v > 0.f ? v : 0.f;
                p += v * w2v[n];
            }
#pragma unroll
            for (int mask = 1; mask < 16; mask <<= 1)
                p += __shfl_xor(p, mask);
            if (lr == 0)
                out[rowbase + m * 16 + lk * 4 + q] = p + b2v;
        }
}

// ---------------- launch ----------------
extern "C" void kernel_launch(void* const* d_in, const int* in_sizes, int n_in,
                              void* d_out, int out_size, void* d_ws, size_t ws_size,
                              hipStream_t stream) {
    (void)in_sizes; (void)n_in; (void)out_size; (void)ws_size;
    const float* X   = (const float*)d_in[0];
    const float* G   = (const float*)d_in[1];
    const float* W1  = (const float*)d_in[2];
    const float* b1  = (const float*)d_in[3];
    const float* W2  = (const float*)d_in[4];
    const float* b2  = (const float*)d_in[5];
    const float* Wm1 = (const float*)d_in[6];
    const float* bm1 = (const float*)d_in[7];
    const float* Wm2 = (const float*)d_in[8];
    const float* bm2 = (const float*)d_in[9];
    float* out = (float*)d_out;

    char* ws = (char*)d_ws;
    u16* Gh   = (u16*)(ws);                     // 33554432 B (bf16 hi)
    u16* W1th = (u16*)(ws + 67108864u);         // 131072 B
    u16* W2th = (u16*)(ws + 67371008u);         // 131072 B
    u16* Tth  = (u16*)(ws + 67633152u);         // 16777216 B (bf16 hi)
    u16* XHh  = (u16*)(ws + 101187584u);        // 16777216 B (X-hi, then H1-hi, then H2-hi)

    // split G and X to bf16-hi (fused); transpose+round W1/W2 (fused)
    splitGX_k<<<3072, 256, 0, stream>>>(G, Gh, X, XHh);
    splitT2_k<<<dim3(256, 2), 256, 0, stream>>>(W1, W1th, W2, W2th);

    // conv1 pre-prop: T1t = bf16((X @ W1 + b1)^T)
    gemm_small_k<<<dim3(2, 256), 256, 0, stream>>>(W1th, XHh, b1, Tth);
    // conv1 prop: H1 = bf16(relu(G @ T1)) (overwrites X buffer)
    gemm_big_k<<<dim3(16, 2, 8), 512, 147456, stream>>>(Gh, Tth, XHh);
    // conv2 pre-prop: T2t = bf16((H1 @ W2 + b2)^T)
    gemm_small_k<<<dim3(2, 256), 256, 0, stream>>>(W2th, XHh, b2, Tth);
    // conv2 prop: H2 = bf16(relu(G @ T2))
    gemm_big_k<<<dim3(16, 2, 8), 512, 147456, stream>>>(Gh, Tth, XHh);
    // final MLP (MFMA)
    mlp_k<<<256, 256, 0, stream>>>(XHh, Wm1, bm1, Wm2, bm2, out);
}

// Round 12
// 181.194 us; speedup vs baseline: 2.0275x; 1.0076x over previous
//
#include <hip/hip_runtime.h>

// Problem constants
#define N_NODES 4096
#define C_IN    256
#define HID     256
#define BATCH   8
#define R_TOT   32768   // BATCH * N_NODES

typedef unsigned short u16;
typedef short s8v  __attribute__((ext_vector_type(8)));   // 8 bf16 (bit pattern in shorts)
typedef float f4v  __attribute__((ext_vector_type(4)));
typedef u16   u16x4 __attribute__((ext_vector_type(4)));

#define MFMA(a,b,c) __builtin_amdgcn_mfma_f32_16x16x32_bf16((a),(b),(c),0,0,0)

__device__ __forceinline__ u16 bf_rne(float x) {
    unsigned u = __float_as_uint(x);
    u += 0x7fffu + ((u >> 16) & 1u);
    return (u16)(u >> 16);
}
__device__ __forceinline__ float bf_f(u16 h) {
    return __uint_as_float(((unsigned)h) << 16);
}

// async global->LDS, 16B per lane. lds ptr must be wave-uniform (dest = base + lane*16)
__device__ __forceinline__ void glds16(const void* g, void* l) {
    __builtin_amdgcn_global_load_lds(
        (const __attribute__((address_space(1))) void*)g,
        (__attribute__((address_space(3))) void*)l, 16, 0, 0);
}

// ---------------- split kernels ----------------

// G (4096x4096) -> bf16 hi. float4-vectorized.
__global__ void splitG_k(const float* __restrict__ G, u16* __restrict__ Gh) {
    const int n4 = 4194304;              // 16M floats / 4
    int i = blockIdx.x * blockDim.x + threadIdx.x;
    const int stride = gridDim.x * blockDim.x;
    for (; i < n4; i += stride) {
        float4 x = ((const float4*)G)[i];
        u16x4 hh;
        hh[0] = bf_rne(x.x); hh[1] = bf_rne(x.y);
        hh[2] = bf_rne(x.z); hh[3] = bf_rne(x.w);
        ((u16x4*)Gh)[i] = hh;
    }
}

// transpose + bf16-round both 256x256 weight matrices: out[h][c] = bf16(in[c][h])
__global__ void splitT2_k(const float* __restrict__ W1, u16* __restrict__ W1th,
                          const float* __restrict__ W2, u16* __restrict__ W2th) {
    const float* in = blockIdx.y ? W2 : W1;
    u16* oh = blockIdx.y ? W2th : W1th;
    const int c = blockIdx.x;      // row of in
    const int h = threadIdx.x;     // col of in
    oh[h * 256 + c] = bf_rne(in[c * 256 + h]);
}

// ---------------- small GEMM v1: B read as fp32 (X), rounded during staging ----------------
// T[i=hid'][j=r] = sum_k W1t[i][k] * bf16(X[j][k]) + bias[i]. Output bf16-hi [256][32768].
__global__ __launch_bounds__(256, 2) void gemm_small1_k(
    const u16* __restrict__ Ah, const float* __restrict__ Bf,
    const float* __restrict__ bias, u16* __restrict__ Oh)
{
    __shared__ u16 sAh[4096], sBh[4096];  // 128x32 each
    const int tid = threadIdx.x;
    const int w = tid >> 6, lane = tid & 63;
    const int i0 = blockIdx.x * 128;   // output row tile (hid')
    const int r0 = blockIdx.y * 128;   // output col tile (r)
    const int lr = lane & 15, lk = lane >> 4;
    const int wr = (w >> 1) * 64, wc = (w & 1) * 64;
    const int kslot = (lk ^ ((lr >> 1) & 3)) * 8;   // swizzled read slot (u16 units)
    const int cb = ((lane & 3) ^ ((lane >> 3) & 3)) * 8;  // pre-swizzled source slot

    const u16 *pAh[2];
#pragma unroll
    for (int j = 0; j < 2; ++j) {
        const int ra = i0 + (w * 2 + j) * 16 + (lane >> 2);
        pAh[j] = Ah + (size_t)ra * 256 + cb;
    }

    f4v acc[4][4] = {};

    for (int kt = 0; kt < 8; ++kt) {
#pragma unroll
        for (int j = 0; j < 2; ++j)
            glds16(pAh[j] + kt * 32, sAh + (w * 2 + j) * 512);
        // B: load fp32, round to bf16, ds_write at swizzled slot (round-1 proven path)
#pragma unroll
        for (int i = 0; i < 4; ++i) {
            const int cc  = tid + i * 256;
            const int row = cc >> 3;
            const int col = (((((cc & 7) >> 1) ^ ((cc >> 4) & 3)) << 3)) | ((cc & 1) * 4);
            const float* src = Bf + (size_t)(r0 + row) * 256 + kt * 32 + (cc & 7) * 4;
            float4 x = *(const float4*)src;
            u16x4 hh;
            hh[0] = bf_rne(x.x); hh[1] = bf_rne(x.y);
            hh[2] = bf_rne(x.z); hh[3] = bf_rne(x.w);
            *(u16x4*)(sBh + row * 32 + col) = hh;
        }
        __syncthreads();

        s8v fah[4], fbh[4];
#pragma unroll
        for (int m = 0; m < 4; ++m) {
            fah[m] = *(const s8v*)(sAh + (wr + m * 16 + lr) * 32 + kslot);
            fbh[m] = *(const s8v*)(sBh + (wc + m * 16 + lr) * 32 + kslot);
        }
#pragma unroll
        for (int m = 0; m < 4; ++m)
#pragma unroll
            for (int n = 0; n < 4; ++n)
                acc[m][n] = MFMA(fah[m], fbh[n], acc[m][n]);
        __syncthreads();
    }

#pragma unroll
    for (int m = 0; m < 4; ++m) {
#pragma unroll
        for (int q = 0; q < 4; ++q) {
            const int rowg = i0 + wr + m * 16 + lk * 4 + q;
            const float bv = bias[rowg];
#pragma unroll
            for (int n = 0; n < 4; ++n) {
                const int colg = r0 + wc + n * 16 + lr;
                float v = acc[m][n][q] + bv;
                Oh[(size_t)rowg * R_TOT + colg] = bf_rne(v);
            }
        }
    }
}

// ---------------- small GEMM v2: both operands bf16 via glds16 (unchanged, proven) ----------------
__global__ __launch_bounds__(256, 2) void gemm_small2_k(
    const u16* __restrict__ Ah, const u16* __restrict__ Bh,
    const float* __restrict__ bias, u16* __restrict__ Oh)
{
    __shared__ u16 sAh[4096], sBh[4096];  // 128x32 each
    const int tid = threadIdx.x;
    const int w = tid >> 6, lane = tid & 63;
    const int i0 = blockIdx.x * 128;
    const int r0 = blockIdx.y * 128;
    const int lr = lane & 15, lk = lane >> 4;
    const int wr = (w >> 1) * 64, wc = (w & 1) * 64;
    const int kslot = (lk ^ ((lr >> 1) & 3)) * 8;
    const int cb = ((lane & 3) ^ ((lane >> 3) & 3)) * 8;

    const u16 *pAh[2], *pBh[2];
#pragma unroll
    for (int j = 0; j < 2; ++j) {
        const int ra = i0 + (w * 2 + j) * 16 + (lane >> 2);
        pAh[j] = Ah + (size_t)ra * 256 + cb;
        const int rb = r0 + (w * 2 + j) * 16 + (lane >> 2);
        pBh[j] = Bh + (size_t)rb * 256 + cb;
    }

    f4v acc[4][4] = {};

    for (int kt = 0; kt < 8; ++kt) {
#pragma unroll
        for (int j = 0; j < 2; ++j) {
            glds16(pAh[j] + kt * 32, sAh + (w * 2 + j) * 512);
            glds16(pBh[j] + kt * 32, sBh + (w * 2 + j) * 512);
        }
        __syncthreads();

        s8v fah[4], fbh[4];
#pragma unroll
        for (int m = 0; m < 4; ++m) {
            fah[m] = *(const s8v*)(sAh + (wr + m * 16 + lr) * 32 + kslot);
            fbh[m] = *(const s8v*)(sBh + (wc + m * 16 + lr) * 32 + kslot);
        }
#pragma unroll
        for (int m = 0; m < 4; ++m)
#pragma unroll
            for (int n = 0; n < 4; ++n)
                acc[m][n] = MFMA(fah[m], fbh[n], acc[m][n]);
        __syncthreads();
    }

#pragma unroll
    for (int m = 0; m < 4; ++m) {
#pragma unroll
        for (int q = 0; q < 4; ++q) {
            const int rowg = i0 + wr + m * 16 + lk * 4 + q;
            const float bv = bias[rowg];
#pragma unroll
            for (int n = 0; n < 4; ++n) {
                const int colg = r0 + wc + n * 16 + lr;
                float v = acc[m][n][q] + bv;
                Oh[(size_t)rowg * R_TOT + colg] = bf_rne(v);
            }
        }
    }
}

// ---------------- big GEMM: H[b][i=n][j=h] = relu( sum_m Ghi[i][m] * Thi[j][b*4096+m] ) ----------------
// Round-10 proven data layout; schedule refined to 4 phases/K-tile (8 MFMA each) with
// ds_reads and glds16 issues distributed per phase. Counted vmcnt(6) once per tile.
// BM=256 BN=128 BK=64, 8 waves (4Mx2N, per-wave 64x64), triple-buffered LDS (3 x 48KB).
// Row = 64 u16 = 128B; swizzle: slot s' = (ks*4+lk) ^ (row&7); source pre-swizzled (l&7)^(l>>3).
__global__ __launch_bounds__(512, 2) void gemm_big_k(
    const u16* __restrict__ Gh, const u16* __restrict__ Th,
    u16* __restrict__ Hh)
{
    extern __shared__ u16 lds[];   // 3 * 24576 u16 = 147456 B
    const int tid = threadIdx.x;
    const int w = tid >> 6, l = tid & 63;
    const int n0 = blockIdx.x * 256;
    const int h0 = blockIdx.y * 128;
    const int b  = blockIdx.z;
    const int lr = l & 15, lk = l >> 4;
    const int wm = w >> 1, wn = w & 1;
    const int sl0 = ((lk)     ^ (lr & 7)) * 8;
    const int sl1 = ((4 + lk) ^ (lr & 7)) * 8;

    const int srow  = l >> 3;
    const int sslot = ((l & 7) ^ srow) * 8;

    const u16* pA0 = Gh + (size_t)(n0 + 8 * w        + srow) * 4096 + sslot;
    const u16* pA1 = Gh + (size_t)(n0 + 8 * (w + 8)  + srow) * 4096 + sslot;
    const u16* pA2 = Gh + (size_t)(n0 + 8 * (w + 16) + srow) * 4096 + sslot;
    const u16* pA3 = Gh + (size_t)(n0 + 8 * (w + 24) + srow) * 4096 + sslot;
    const u16* pB0 = Th + (size_t)(h0 + 8 * w       + srow) * R_TOT + (size_t)b * 4096 + sslot;
    const u16* pB1 = Th + (size_t)(h0 + 8 * (w + 8) + srow) * R_TOT + (size_t)b * 4096 + sslot;

    const int dA0 = w * 512, dA1 = (w + 8) * 512, dA2 = (w + 16) * 512, dA3 = (w + 24) * 512;
    const int dB0 = 16384 + w * 512, dB1 = 16384 + (w + 8) * 512;

    f4v acc[4][4] = {};

#define STAGE6(STG) do {                                                       \
    u16* Ls = lds + (STG) * 24576;                                             \
    glds16(pA0, Ls + dA0); glds16(pA1, Ls + dA1);                              \
    glds16(pA2, Ls + dA2); glds16(pA3, Ls + dA3);                              \
    glds16(pB0, Ls + dB0); glds16(pB1, Ls + dB1);                              \
    pA0 += 64; pA1 += 64; pA2 += 64; pA3 += 64; pB0 += 64; pB1 += 64;          \
} while (0)

#define BAR()  __builtin_amdgcn_s_barrier()
#define PRIO1() __builtin_amdgcn_s_setprio(1)
#define PRIO0() __builtin_amdgcn_s_setprio(0)

// One K-tile: 4 phases x 8 MFMA. VMODE: 0 = vmcnt(6), 1 = vmcnt(0), 2 = skip.
#define KTILE(CUR, STG, DO_STAGE, VMODE) do {                                  \
    const u16* Lc = lds + (CUR) * 24576;                                       \
    u16* Ls = lds + (STG) * 24576;                                             \
    s8v fa0[2], fa1[2], fb0[4], fb1[4];                                        \
    /* P0: read A m0,m1 + B (ks0); stage A0,A1 */                              \
    _Pragma("unroll") for (int m = 0; m < 2; ++m)                              \
        fa0[m] = *(const s8v*)(Lc + (wm * 64 + m * 16 + lr) * 64 + sl0);       \
    _Pragma("unroll") for (int n = 0; n < 4; ++n)                              \
        fb0[n] = *(const s8v*)(Lc + 16384 + (wn * 64 + n * 16 + lr) * 64 + sl0); \
    if (DO_STAGE) { glds16(pA0, Ls + dA0); glds16(pA1, Ls + dA1); }            \
    BAR(); PRIO1();                                                            \
    _Pragma("unroll") for (int m = 0; m < 2; ++m)                              \
        _Pragma("unroll") for (int n = 0; n < 4; ++n)                          \
            acc[m][n] = MFMA(fa0[m], fb0[n], acc[m][n]);                       \
    PRIO0(); BAR();                                                            \
    /* P1: read A m2,m3 (ks0); stage A2,A3 */                                  \
    _Pragma("unroll") for (int m = 0; m < 2; ++m)                              \
        fa1[m] = *(const s8v*)(Lc + (wm * 64 + (m + 2) * 16 + lr) * 64 + sl0); \
    if (DO_STAGE) { glds16(pA2, Ls + dA2); glds16(pA3, Ls + dA3); }            \
    BAR(); PRIO1();                                                            \
    _Pragma("unroll") for (int m = 0; m < 2; ++m)                              \
        _Pragma("unroll") for (int n = 0; n < 4; ++n)                          \
            acc[m + 2][n] = MFMA(fa1[m], fb0[n], acc[m + 2][n]);               \
    PRIO0(); BAR();                                                            \
    /* P2: read A m0,m1 + B (ks1); stage B0 */                                 \
    _Pragma("unroll") for (int m = 0; m < 2; ++m)                              \
        fa0[m] = *(const s8v*)(Lc + (wm * 64 + m * 16 + lr) * 64 + sl1);       \
    _Pragma("unroll") for (int n = 0; n < 4; ++n)                              \
        fb1[n] = *(const s8v*)(Lc + 16384 + (wn * 64 + n * 16 + lr) * 64 + sl1); \
    if (DO_STAGE) { glds16(pB0, Ls + dB0); }                                   \
    BAR(); PRIO1();                                                            \
    _Pragma("unroll") for (int m = 0; m < 2; ++m)                              \
        _Pragma("unroll") for (int n = 0; n < 4; ++n)                          \
            acc[m][n] = MFMA(fa0[m], fb1[n], acc[m][n]);                       \
    PRIO0(); BAR();                                                            \
    /* P3: read A m2,m3 (ks1); stage B1, advance ptrs */                       \
    _Pragma("unroll") for (int m = 0; m < 2; ++m)                              \
        fa1[m] = *(const s8v*)(Lc + (wm * 64 + (m + 2) * 16 + lr) * 64 + sl1); \
    if (DO_STAGE) { glds16(pB1, Ls + dB1);                                     \
        pA0 += 64; pA1 += 64; pA2 += 64; pA3 += 64; pB0 += 64; pB1 += 64; }    \
    BAR(); PRIO1();                                                            \
    _Pragma("unroll") for (int m = 0; m < 2; ++m)                              \
        _Pragma("unroll") for (int n = 0; n < 4; ++n)                          \
            acc[m + 2][n] = MFMA(fa1[m], fb1[n], acc[m + 2][n]);               \
    PRIO0();                                                                   \
    if (VMODE == 0)      asm volatile("s_waitcnt vmcnt(6)" ::: "memory");      \
    else if (VMODE == 1) asm volatile("s_waitcnt vmcnt(0)" ::: "memory");      \
    if (VMODE != 2) BAR();                                                     \
    __builtin_amdgcn_sched_barrier(0);                                         \
} while (0)

    // prologue: stage tiles 0 (buf0) and 1 (buf1); 12 loads in flight per wave
    STAGE6(0);
    STAGE6(1);
    asm volatile("s_waitcnt vmcnt(6)" ::: "memory");   // tile-0 loads landed
    BAR();
    __builtin_amdgcn_sched_barrier(0);

    // 64 K-tiles: t in buf t%3, staging t+2 while computing t (t <= 61)
    for (int it = 0; it < 20; ++it) {
        KTILE(0, 2, 1, 0);
        KTILE(1, 0, 1, 0);
        KTILE(2, 1, 1, 0);
    }
    KTILE(0, 2, 1, 0);   // t=60, stages 62
    KTILE(1, 0, 1, 0);   // t=61, stages 63
    KTILE(2, 1, 0, 1);   // t=62, drain tile-63 loads
    KTILE(0, 2, 0, 2);   // t=63

#undef STAGE6
#undef KTILE
#undef BAR
#undef PRIO1
#undef PRIO0

    // epilogue: relu, round, store H as bf16-hi [b*4096+row][col]
    const size_t obase = ((size_t)b * 4096 + n0 + wm * 64 + lk * 4) * 256
                       + h0 + wn * 64 + lr;
#pragma unroll
    for (int m = 0; m < 4; ++m)
#pragma unroll
        for (int n = 0; n < 4; ++n)
#pragma unroll
            for (int q = 0; q < 4; ++q) {
                float v = acc[m][n][q];
                v = v > 0.f ? v : 0.f;
                Hh[obase + (size_t)(m * 16 + q) * 256 + n * 16] = bf_rne(v);
            }
}

// ---------------- final MLP (MFMA): out[r] = relu(H[r,:] @ Wm1 + bm1) @ Wm2 + bm2 ----------------
__global__ __launch_bounds__(256) void mlp_k(
    const u16* __restrict__ Hh, const float* __restrict__ Wm1,
    const float* __restrict__ bm1, const float* __restrict__ Wm2,
    const float* __restrict__ bm2, float* __restrict__ out)
{
    __shared__ u16 sB[16384];   // Wm1t bf16, swizzled: [col 64][k 256]
    const int tid = threadIdx.x;
    const int w = tid >> 6, l = tid & 63;
    const int lr = l & 15, lk = l >> 4;

    for (int idx = tid; idx < 16384; idx += 256) {
        const int col = idx & 63, k = idx >> 6;
        const int slot = (k >> 3) ^ (col & 7);
        sB[col * 256 + slot * 8 + (k & 7)] = bf_rne(Wm1[k * 64 + col]);
    }
    __syncthreads();

    float bm1v[4], w2v[4];
#pragma unroll
    for (int n = 0; n < 4; ++n) {
        bm1v[n] = bm1[n * 16 + lr];
        w2v[n]  = Wm2[n * 16 + lr];
    }
    const float b2v = bm2[0];

    const int rowbase = blockIdx.x * 128 + w * 32;
    f4v acc[2][4] = {};
#pragma unroll
    for (int ks = 0; ks < 8; ++ks) {
        s8v fa[2], fb[4];
#pragma unroll
        for (int m = 0; m < 2; ++m)
            fa[m] = *(const s8v*)(Hh + (size_t)(rowbase + m * 16 + lr) * 256 + ks * 32 + lk * 8);
        const int slot = ((ks * 4 + lk) ^ (lr & 7)) * 8;
#pragma unroll
        for (int n = 0; n < 4; ++n)
            fb[n] = *(const s8v*)(sB + (n * 16 + lr) * 256 + slot);
#pragma unroll
        for (int m = 0; m < 2; ++m)
#pragma unroll
            for (int n = 0; n < 4; ++n)
                acc[m][n] = MFMA(fa[m], fb[n], acc[m][n]);
    }

#pragma unroll
    for (int m = 0; m < 2; ++m)
#pragma unroll
        for (int q = 0; q < 4; ++q) {
            float p = 0.f;
#pragma unroll
            for (int n = 0; n < 4; ++n) {
                float v = acc[m][n][q] + bm1v[n];
                v = v > 0.f ? v : 0.f;
                p += v * w2v[n];
            }
#pragma unroll
            for (int mask = 1; mask < 16; mask <<= 1)
                p += __shfl_xor(p, mask);
            if (lr == 0)
                out[rowbase + m * 16 + lk * 4 + q] = p + b2v;
        }
}

// ---------------- launch ----------------
extern "C" void kernel_launch(void* const* d_in, const int* in_sizes, int n_in,
                              void* d_out, int out_size, void* d_ws, size_t ws_size,
                              hipStream_t stream) {
    (void)in_sizes; (void)n_in; (void)out_size; (void)ws_size;
    const float* X   = (const float*)d_in[0];
    const float* G   = (const float*)d_in[1];
    const float* W1  = (const float*)d_in[2];
    const float* b1  = (const float*)d_in[3];
    const float* W2  = (const float*)d_in[4];
    const float* b2  = (const float*)d_in[5];
    const float* Wm1 = (const float*)d_in[6];
    const float* bm1 = (const float*)d_in[7];
    const float* Wm2 = (const float*)d_in[8];
    const float* bm2 = (const float*)d_in[9];
    float* out = (float*)d_out;

    char* ws = (char*)d_ws;
    u16* Gh   = (u16*)(ws);                     // 33554432 B (bf16 hi)
    u16* W1th = (u16*)(ws + 67108864u);         // 131072 B
    u16* W2th = (u16*)(ws + 67371008u);         // 131072 B
    u16* Tth  = (u16*)(ws + 67633152u);         // 16777216 B (bf16 hi)
    u16* Hh   = (u16*)(ws + 101187584u);        // 16777216 B (H1-hi, then H2-hi)

    // split G to bf16-hi; transpose+round W1/W2 (fused)
    splitG_k<<<2048, 256, 0, stream>>>(G, Gh);
    splitT2_k<<<dim3(256, 2), 256, 0, stream>>>(W1, W1th, W2, W2th);

    // conv1 pre-prop: T1t = bf16((X @ W1 + b1)^T)   (X read fp32, rounded in-kernel)
    gemm_small1_k<<<dim3(2, 256), 256, 0, stream>>>(W1th, X, b1, Tth);
    // conv1 prop: H1 = bf16(relu(G @ T1))
    gemm_big_k<<<dim3(16, 2, 8), 512, 147456, stream>>>(Gh, Tth, Hh);
    // conv2 pre-prop: T2t = bf16((H1 @ W2 + b2)^T)
    gemm_small2_k<<<dim3(2, 256), 256, 0, stream>>>(W2th, Hh, b2, Tth);
    // conv2 prop: H2 = bf16(relu(G @ T2))
    gemm_big_k<<<dim3(16, 2, 8), 512, 147456, stream>>>(Gh, Tth, Hh);
    // final MLP (MFMA)
    mlp_k<<<256, 256, 0, stream>>>(Hh, Wm1, bm1, Wm2, bm2, out);
}

// Round 13
// 179.314 us; speedup vs baseline: 2.0487x; 1.0105x over previous
//
#include <hip/hip_runtime.h>

// Problem constants
#define N_NODES 4096
#define C_IN    256
#define HID     256
#define BATCH   8
#define R_TOT   32768   // BATCH * N_NODES

typedef unsigned short u16;
typedef short s8v  __attribute__((ext_vector_type(8)));   // 8 bf16 (bit pattern in shorts)
typedef float f4v  __attribute__((ext_vector_type(4)));
typedef u16   u16x4 __attribute__((ext_vector_type(4)));

#define MFMA(a,b,c) __builtin_amdgcn_mfma_f32_16x16x32_bf16((a),(b),(c),0,0,0)

__device__ __forceinline__ u16 bf_rne(float x) {
    unsigned u = __float_as_uint(x);
    u += 0x7fffu + ((u >> 16) & 1u);
    return (u16)(u >> 16);
}
__device__ __forceinline__ float bf_f(u16 h) {
    return __uint_as_float(((unsigned)h) << 16);
}

// async global->LDS, 16B per lane. lds ptr must be wave-uniform (dest = base + lane*16)
__device__ __forceinline__ void glds16(const void* g, void* l) {
    __builtin_amdgcn_global_load_lds(
        (const __attribute__((address_space(1))) void*)g,
        (__attribute__((address_space(3))) void*)l, 16, 0, 0);
}

// ---------------- split kernels ----------------

// G (4096x4096) -> bf16 hi. float4-vectorized.
__global__ void splitG_k(const float* __restrict__ G, u16* __restrict__ Gh) {
    const int n4 = 4194304;              // 16M floats / 4
    int i = blockIdx.x * blockDim.x + threadIdx.x;
    const int stride = gridDim.x * blockDim.x;
    for (; i < n4; i += stride) {
        float4 x = ((const float4*)G)[i];
        u16x4 hh;
        hh[0] = bf_rne(x.x); hh[1] = bf_rne(x.y);
        hh[2] = bf_rne(x.z); hh[3] = bf_rne(x.w);
        ((u16x4*)Gh)[i] = hh;
    }
}

// transpose + bf16-round both 256x256 weight matrices: out[h][c] = bf16(in[c][h])
__global__ void splitT2_k(const float* __restrict__ W1, u16* __restrict__ W1th,
                          const float* __restrict__ W2, u16* __restrict__ W2th) {
    const float* in = blockIdx.y ? W2 : W1;
    u16* oh = blockIdx.y ? W2th : W1th;
    const int c = blockIdx.x;      // row of in
    const int h = threadIdx.x;     // col of in
    oh[h * 256 + c] = bf_rne(in[c * 256 + h]);
}

// ---------------- small GEMM v1: B read as fp32 (X), rounded during staging ----------------
// T[i=hid'][j=r] = sum_k W1t[i][k] * bf16(X[j][k]) + bias[i]. Output bf16-hi [256][32768].
__global__ __launch_bounds__(256, 2) void gemm_small1_k(
    const u16* __restrict__ Ah, const float* __restrict__ Bf,
    const float* __restrict__ bias, u16* __restrict__ Oh)
{
    __shared__ u16 sAh[4096], sBh[4096];  // 128x32 each
    const int tid = threadIdx.x;
    const int w = tid >> 6, lane = tid & 63;
    const int i0 = blockIdx.x * 128;   // output row tile (hid')
    const int r0 = blockIdx.y * 128;   // output col tile (r)
    const int lr = lane & 15, lk = lane >> 4;
    const int wr = (w >> 1) * 64, wc = (w & 1) * 64;
    const int kslot = (lk ^ ((lr >> 1) & 3)) * 8;   // swizzled read slot (u16 units)
    const int cb = ((lane & 3) ^ ((lane >> 3) & 3)) * 8;  // pre-swizzled source slot

    const u16 *pAh[2];
#pragma unroll
    for (int j = 0; j < 2; ++j) {
        const int ra = i0 + (w * 2 + j) * 16 + (lane >> 2);
        pAh[j] = Ah + (size_t)ra * 256 + cb;
    }

    f4v acc[4][4] = {};

    for (int kt = 0; kt < 8; ++kt) {
#pragma unroll
        for (int j = 0; j < 2; ++j)
            glds16(pAh[j] + kt * 32, sAh + (w * 2 + j) * 512);
        // B: load fp32, round to bf16, ds_write at swizzled slot (round-1 proven path)
#pragma unroll
        for (int i = 0; i < 4; ++i) {
            const int cc  = tid + i * 256;
            const int row = cc >> 3;
            const int col = (((((cc & 7) >> 1) ^ ((cc >> 4) & 3)) << 3)) | ((cc & 1) * 4);
            const float* src = Bf + (size_t)(r0 + row) * 256 + kt * 32 + (cc & 7) * 4;
            float4 x = *(const float4*)src;
            u16x4 hh;
            hh[0] = bf_rne(x.x); hh[1] = bf_rne(x.y);
            hh[2] = bf_rne(x.z); hh[3] = bf_rne(x.w);
            *(u16x4*)(sBh + row * 32 + col) = hh;
        }
        __syncthreads();

        s8v fah[4], fbh[4];
#pragma unroll
        for (int m = 0; m < 4; ++m) {
            fah[m] = *(const s8v*)(sAh + (wr + m * 16 + lr) * 32 + kslot);
            fbh[m] = *(const s8v*)(sBh + (wc + m * 16 + lr) * 32 + kslot);
        }
#pragma unroll
        for (int m = 0; m < 4; ++m)
#pragma unroll
            for (int n = 0; n < 4; ++n)
                acc[m][n] = MFMA(fah[m], fbh[n], acc[m][n]);
        __syncthreads();
    }

#pragma unroll
    for (int m = 0; m < 4; ++m) {
#pragma unroll
        for (int q = 0; q < 4; ++q) {
            const int rowg = i0 + wr + m * 16 + lk * 4 + q;
            const float bv = bias[rowg];
#pragma unroll
            for (int n = 0; n < 4; ++n) {
                const int colg = r0 + wc + n * 16 + lr;
                float v = acc[m][n][q] + bv;
                Oh[(size_t)rowg * R_TOT + colg] = bf_rne(v);
            }
        }
    }
}

// ---------------- small GEMM v2: both operands bf16 via glds16 (unchanged, proven) ----------------
__global__ __launch_bounds__(256, 2) void gemm_small2_k(
    const u16* __restrict__ Ah, const u16* __restrict__ Bh,
    const float* __restrict__ bias, u16* __restrict__ Oh)
{
    __shared__ u16 sAh[4096], sBh[4096];  // 128x32 each
    const int tid = threadIdx.x;
    const int w = tid >> 6, lane = tid & 63;
    const int i0 = blockIdx.x * 128;
    const int r0 = blockIdx.y * 128;
    const int lr = lane & 15, lk = lane >> 4;
    const int wr = (w >> 1) * 64, wc = (w & 1) * 64;
    const int kslot = (lk ^ ((lr >> 1) & 3)) * 8;
    const int cb = ((lane & 3) ^ ((lane >> 3) & 3)) * 8;

    const u16 *pAh[2], *pBh[2];
#pragma unroll
    for (int j = 0; j < 2; ++j) {
        const int ra = i0 + (w * 2 + j) * 16 + (lane >> 2);
        pAh[j] = Ah + (size_t)ra * 256 + cb;
        const int rb = r0 + (w * 2 + j) * 16 + (lane >> 2);
        pBh[j] = Bh + (size_t)rb * 256 + cb;
    }

    f4v acc[4][4] = {};

    for (int kt = 0; kt < 8; ++kt) {
#pragma unroll
        for (int j = 0; j < 2; ++j) {
            glds16(pAh[j] + kt * 32, sAh + (w * 2 + j) * 512);
            glds16(pBh[j] + kt * 32, sBh + (w * 2 + j) * 512);
        }
        __syncthreads();

        s8v fah[4], fbh[4];
#pragma unroll
        for (int m = 0; m < 4; ++m) {
            fah[m] = *(const s8v*)(sAh + (wr + m * 16 + lr) * 32 + kslot);
            fbh[m] = *(const s8v*)(sBh + (wc + m * 16 + lr) * 32 + kslot);
        }
#pragma unroll
        for (int m = 0; m < 4; ++m)
#pragma unroll
            for (int n = 0; n < 4; ++n)
                acc[m][n] = MFMA(fah[m], fbh[n], acc[m][n]);
        __syncthreads();
    }

#pragma unroll
    for (int m = 0; m < 4; ++m) {
#pragma unroll
        for (int q = 0; q < 4; ++q) {
            const int rowg = i0 + wr + m * 16 + lk * 4 + q;
            const float bv = bias[rowg];
#pragma unroll
            for (int n = 0; n < 4; ++n) {
                const int colg = r0 + wc + n * 16 + lr;
                float v = acc[m][n][q] + bv;
                Oh[(size_t)rowg * R_TOT + colg] = bf_rne(v);
            }
        }
    }
}

// ---------------- big GEMM: H[b][i=n][j=h] = relu( sum_m Ghi[i][m] * Thi[j][b*4096+m] ) ----------------
// Round-10 proven kernel (2 phases/K-tile — the 4-phase variant of r11 regressed).
// Pure bf16. BM=256 BN=128 BK=64, 8 waves (4Mx2N, per-wave 64x64), triple-buffered LDS
// (3 x 48KB), counted vmcnt(6), setprio around MFMA. Row = 64 u16 = 128B;
// swizzle: slot s' = (ks*4+lk) ^ (row&7); source pre-swizzled (l&7)^(l>>3).
// Buffer layout (u16): [A 256x64 | B 128x64] = 24576 u16 = 48KB. Output: bf16-hi only.
__global__ __launch_bounds__(512, 2) void gemm_big_k(
    const u16* __restrict__ Gh, const u16* __restrict__ Th,
    u16* __restrict__ Hh)
{
    extern __shared__ u16 lds[];   // 3 * 24576 u16 = 147456 B
    const int tid = threadIdx.x;
    const int w = tid >> 6, l = tid & 63;
    const int n0 = blockIdx.x * 256;
    const int h0 = blockIdx.y * 128;
    const int b  = blockIdx.z;
    const int lr = l & 15, lk = l >> 4;
    const int wm = w >> 1, wn = w & 1;
    // fragment read slots (u16 units): s' = (ks*4+lk) ^ (lr&7)
    const int sl0 = ((lk)     ^ (lr & 7)) * 8;
    const int sl1 = ((4 + lk) ^ (lr & 7)) * 8;

    // staging: per-lane source swizzle (chunk = 8 rows x 64 u16)
    const int srow  = l >> 3;                   // row within chunk
    const int sslot = ((l & 7) ^ srow) * 8;     // source col slot (u16)

    // A chunks c = w, w+8, w+16, w+24 (rows 8c..8c+7); B chunks c = w, w+8
    const u16* pA0 = Gh + (size_t)(n0 + 8 * w        + srow) * 4096 + sslot;
    const u16* pA1 = Gh + (size_t)(n0 + 8 * (w + 8)  + srow) * 4096 + sslot;
    const u16* pA2 = Gh + (size_t)(n0 + 8 * (w + 16) + srow) * 4096 + sslot;
    const u16* pA3 = Gh + (size_t)(n0 + 8 * (w + 24) + srow) * 4096 + sslot;
    const u16* pB0 = Th + (size_t)(h0 + 8 * w       + srow) * R_TOT + (size_t)b * 4096 + sslot;
    const u16* pB1 = Th + (size_t)(h0 + 8 * (w + 8) + srow) * R_TOT + (size_t)b * 4096 + sslot;

    // wave-uniform LDS chunk bases (u16)
    const int dA0 = w * 512, dA1 = (w + 8) * 512, dA2 = (w + 16) * 512, dA3 = (w + 24) * 512;
    const int dB0 = 16384 + w * 512, dB1 = 16384 + (w + 8) * 512;

    f4v acc[4][4] = {};

#define STAGE6(STG) do {                                                       \
    u16* Ls = lds + (STG) * 24576;                                             \
    glds16(pA0, Ls + dA0); glds16(pA1, Ls + dA1);                              \
    glds16(pA2, Ls + dA2); glds16(pA3, Ls + dA3);                              \
    glds16(pB0, Ls + dB0); glds16(pB1, Ls + dB1);                              \
    pA0 += 64; pA1 += 64; pA2 += 64; pA3 += 64; pB0 += 64; pB1 += 64;          \
} while (0)

// One K-tile: 2 phases. VMODE: 0 = vmcnt(6) (steady), 1 = vmcnt(0) (drain), 2 = skip.
#define KTILE(CUR, STG, DO_STAGE, VMODE) do {                                  \
    const u16* Lc = lds + (CUR) * 24576;                                       \
    u16* Ls = lds + (STG) * 24576;                                             \
    /* P0: ks0 fragments; stage first 3 chunks */                              \
    { s8v fa[4], fb[4];                                                        \
      _Pragma("unroll") for (int m = 0; m < 4; ++m)                            \
          fa[m] = *(const s8v*)(Lc + (wm * 64 + m * 16 + lr) * 64 + sl0);      \
      _Pragma("unroll") for (int n = 0; n < 4; ++n)                            \
          fb[n] = *(const s8v*)(Lc + 16384 + (wn * 64 + n * 16 + lr) * 64 + sl0); \
      if (DO_STAGE) { glds16(pA0, Ls + dA0); glds16(pA1, Ls + dA1);            \
                      glds16(pB0, Ls + dB0); }                                 \
      __builtin_amdgcn_s_barrier();                                            \
      __builtin_amdgcn_s_setprio(1);                                           \
      _Pragma("unroll") for (int m = 0; m < 4; ++m)                            \
          _Pragma("unroll") for (int n = 0; n < 4; ++n)                        \
              acc[m][n] = MFMA(fa[m], fb[n], acc[m][n]);                       \
      __builtin_amdgcn_s_setprio(0);                                           \
      __builtin_amdgcn_s_barrier(); }                                          \
    /* P1: ks1 fragments; stage last 3 chunks, advance ptrs */                 \
    { s8v fa[4], fb[4];                                                        \
      _Pragma("unroll") for (int m = 0; m < 4; ++m)                            \
          fa[m] = *(const s8v*)(Lc + (wm * 64 + m * 16 + lr) * 64 + sl1);      \
      _Pragma("unroll") for (int n = 0; n < 4; ++n)                            \
          fb[n] = *(const s8v*)(Lc + 16384 + (wn * 64 + n * 16 + lr) * 64 + sl1); \
      if (DO_STAGE) { glds16(pA2, Ls + dA2); glds16(pA3, Ls + dA3);            \
                      glds16(pB1, Ls + dB1);                                   \
                      pA0 += 64; pA1 += 64; pA2 += 64; pA3 += 64;              \
                      pB0 += 64; pB1 += 64; }                                  \
      __builtin_amdgcn_s_barrier();                                            \
      __builtin_amdgcn_s_setprio(1);                                           \
      _Pragma("unroll") for (int m = 0; m < 4; ++m)                            \
          _Pragma("unroll") for (int n = 0; n < 4; ++n)                        \
              acc[m][n] = MFMA(fa[m], fb[n], acc[m][n]);                       \
      __builtin_amdgcn_s_setprio(0); }                                         \
    if (VMODE == 0)      asm volatile("s_waitcnt vmcnt(6)" ::: "memory");      \
    else if (VMODE == 1) asm volatile("s_waitcnt vmcnt(0)" ::: "memory");      \
    if (VMODE != 2) __builtin_amdgcn_s_barrier();                              \
    __builtin_amdgcn_sched_barrier(0);                                         \
} while (0)

    // prologue: stage tiles 0 (buf0) and 1 (buf1); 12 loads in flight per wave
    STAGE6(0);
    STAGE6(1);
    asm volatile("s_waitcnt vmcnt(6)" ::: "memory");   // tile-0 loads landed
    __builtin_amdgcn_s_barrier();
    __builtin_amdgcn_sched_barrier(0);

    // 64 K-tiles: t in buf t%3, staging t+2 while computing t (t <= 61)
    for (int it = 0; it < 20; ++it) {
        KTILE(0, 2, 1, 0);
        KTILE(1, 0, 1, 0);
        KTILE(2, 1, 1, 0);
    }
    KTILE(0, 2, 1, 0);   // t=60, stages 62
    KTILE(1, 0, 1, 0);   // t=61, stages 63
    KTILE(2, 1, 0, 1);   // t=62, drain tile-63 loads
    KTILE(0, 2, 0, 2);   // t=63

#undef STAGE6
#undef KTILE

    // epilogue: relu, round, store H as bf16-hi [b*4096+row][col]
    const size_t obase = ((size_t)b * 4096 + n0 + wm * 64 + lk * 4) * 256
                       + h0 + wn * 64 + lr;
#pragma unroll
    for (int m = 0; m < 4; ++m)
#pragma unroll
        for (int n = 0; n < 4; ++n)
#pragma unroll
            for (int q = 0; q < 4; ++q) {
                float v = acc[m][n][q];
                v = v > 0.f ? v : 0.f;
                Hh[obase + (size_t)(m * 16 + q) * 256 + n * 16] = bf_rne(v);
            }
}

// ---------------- final MLP (MFMA): out[r] = relu(H[r,:] @ Wm1 + bm1) @ Wm2 + bm2 ----------------
__global__ __launch_bounds__(256) void mlp_k(
    const u16* __restrict__ Hh, const float* __restrict__ Wm1,
    const float* __restrict__ bm1, const float* __restrict__ Wm2,
    const float* __restrict__ bm2, float* __restrict__ out)
{
    __shared__ u16 sB[16384];   // Wm1t bf16, swizzled: [col 64][k 256]
    const int tid = threadIdx.x;
    const int w = tid >> 6, l = tid & 63;
    const int lr = l & 15, lk = l >> 4;

    for (int idx = tid; idx < 16384; idx += 256) {
        const int col = idx & 63, k = idx >> 6;
        const int slot = (k >> 3) ^ (col & 7);
        sB[col * 256 + slot * 8 + (k & 7)] = bf_rne(Wm1[k * 64 + col]);
    }
    __syncthreads();

    float bm1v[4], w2v[4];
#pragma unroll
    for (int n = 0; n < 4; ++n) {
        bm1v[n] = bm1[n * 16 + lr];
        w2v[n]  = Wm2[n * 16 + lr];
    }
    const float b2v = bm2[0];

    const int rowbase = blockIdx.x * 128 + w * 32;
    f4v acc[2][4] = {};
#pragma unroll
    for (int ks = 0; ks < 8; ++ks) {
        s8v fa[2], fb[4];
#pragma unroll
        for (int m = 0; m < 2; ++m)
            fa[m] = *(const s8v*)(Hh + (size_t)(rowbase + m * 16 + lr) * 256 + ks * 32 + lk * 8);
        const int slot = ((ks * 4 + lk) ^ (lr & 7)) * 8;
#pragma unroll
        for (int n = 0; n < 4; ++n)
            fb[n] = *(const s8v*)(sB + (n * 16 + lr) * 256 + slot);
#pragma unroll
        for (int m = 0; m < 2; ++m)
#pragma unroll
            for (int n = 0; n < 4; ++n)
                acc[m][n] = MFMA(fa[m], fb[n], acc[m][n]);
    }

#pragma unroll
    for (int m = 0; m < 2; ++m)
#pragma unroll
        for (int q = 0; q < 4; ++q) {
            float p = 0.f;
#pragma unroll
            for (int n = 0; n < 4; ++n) {
                float v = acc[m][n][q] + bm1v[n];
                v = v > 0.f ? v : 0.f;
                p += v * w2v[n];
            }
#pragma unroll
            for (int mask = 1; mask < 16; mask <<= 1)
                p += __shfl_xor(p, mask);
            if (lr == 0)
                out[rowbase + m * 16 + lk * 4 + q] = p + b2v;
        }
}

// ---------------- launch ----------------
extern "C" void kernel_launch(void* const* d_in, const int* in_sizes, int n_in,
                              void* d_out, int out_size, void* d_ws, size_t ws_size,
                              hipStream_t stream) {
    (void)in_sizes; (void)n_in; (void)out_size; (void)ws_size;
    const float* X   = (const float*)d_in[0];
    const float* G   = (const float*)d_in[1];
    const float* W1  = (const float*)d_in[2];
    const float* b1  = (const float*)d_in[3];
    const float* W2  = (const float*)d_in[4];
    const float* b2  = (const float*)d_in[5];
    const float* Wm1 = (const float*)d_in[6];
    const float* bm1 = (const float*)d_in[7];
    const float* Wm2 = (const float*)d_in[8];
    const float* bm2 = (const float*)d_in[9];
    float* out = (float*)d_out;

    char* ws = (char*)d_ws;
    u16* Gh   = (u16*)(ws);                     // 33554432 B (bf16 hi)
    u16* W1th = (u16*)(ws + 67108864u);         // 131072 B
    u16* W2th = (u16*)(ws + 67371008u);         // 131072 B
    u16* Tth  = (u16*)(ws + 67633152u);         // 16777216 B (bf16 hi)
    u16* Hh   = (u16*)(ws + 101187584u);        // 16777216 B (H1-hi, then H2-hi)

    // split G to bf16-hi; transpose+round W1/W2 (fused)
    splitG_k<<<2048, 256, 0, stream>>>(G, Gh);
    splitT2_k<<<dim3(256, 2), 256, 0, stream>>>(W1, W1th, W2, W2th);

    // conv1 pre-prop: T1t = bf16((X @ W1 + b1)^T)   (X read fp32, rounded in-kernel)
    gemm_small1_k<<<dim3(2, 256), 256, 0, stream>>>(W1th, X, b1, Tth);
    // conv1 prop: H1 = bf16(relu(G @ T1))
    gemm_big_k<<<dim3(16, 2, 8), 512, 147456, stream>>>(Gh, Tth, Hh);
    // conv2 pre-prop: T2t = bf16((H1 @ W2 + b2)^T)
    gemm_small2_k<<<dim3(2, 256), 256, 0, stream>>>(W2th, Hh, b2, Tth);
    // conv2 prop: H2 = bf16(relu(G @ T2))
    gemm_big_k<<<dim3(16, 2, 8), 512, 147456, stream>>>(Gh, Tth, Hh);
    // final MLP (MFMA)
    mlp_k<<<256, 256, 0, stream>>>(Hh, Wm1, bm1, Wm2, bm2, out);
}